// Round 6
// baseline (191.305 us; speedup 1.0000x reference)
//
#include <hip/hip_runtime.h>
#include <hip/hip_bf16.h>

typedef __attribute__((ext_vector_type(8))) short short8;
typedef __attribute__((ext_vector_type(4))) float floatx4;

#define F_IN 256
#define F_OUT 128
#define NODE_SHIFT 6               // 64 nodes per bucket
#define BKT_NODES 64
#define MAX_BKT 2048
#define BIN_BLOCKS 256             // hetero kernel: blocks [0,BIN_BLOCKS) do bincount
#define GEMM_BLOCKS 512            // blocks [BIN_BLOCKS, BIN_BLOCKS+GEMM_BLOCKS) do gemm

static __device__ __forceinline__ short f32_to_bf16_bits(float v) {
    __hip_bfloat16 t = __float2bfloat16(v);
    return *reinterpret_cast<short*>(&t);
}
static __device__ __forceinline__ float bf16bits_to_f32(unsigned short u) {
    unsigned x = (unsigned)u << 16;
    return __builtin_bit_cast(float, x);
}

// Deterministic input-dtype probe + zero bucket_counts (folds the memset).
// flags[0]: 1 = floats are f32, 0 = floats are bf16
// flags[1]: 1 = indices are int64, 0 = int32
__global__ __launch_bounds__(256) void detect_kernel(
    const void* __restrict__ featp, const void* __restrict__ dstp,
    int* __restrict__ flags, int* __restrict__ bucket_counts, int nbkt)
{
    for (int j = threadIdx.x; j < nbkt; j += 256) bucket_counts[j] = 0;
    if (threadIdx.x == 0) {
        const unsigned short* fb = (const unsigned short*)featp;
        int plaus = 0;
        for (int i = 0; i < 64; ++i) {
            unsigned short u = fb[2 * i];
            int ex = (u >> 7) & 0xFF;
            if (ex >= 118 && ex <= 137) plaus++;
        }
        flags[0] = (plaus >= 48) ? 0 : 1;

        const int* di = (const int*)dstp;
        int zeros = 0;
        for (int i = 0; i < 64; ++i)
            if (di[2 * i + 1] == 0) zeros++;
        flags[1] = (zeros >= 62) ? 1 : 0;
    }
}

// Heterogeneous kernel:
//   blocks [0, BIN_BLOCKS):           LDS-histogram of dst>>NODE_SHIFT
//   blocks [BIN_BLOCKS, +GEMM_BLOCKS): h = feat @ w^T via MFMA, w staged in LDS
__global__ __launch_bounds__(256) void gemm_bincount_kernel(
    const void* __restrict__ featp, const void* __restrict__ wp,
    unsigned short* __restrict__ hp, int n_nodes, int n_tiles,
    const void* __restrict__ dstp, int* __restrict__ bucket_counts,
    int n_edges, int nbkt, const int* __restrict__ flags)
{
    __shared__ short8 smem8[4096];   // 64 KB shared between both roles
    char* smem = (char*)smem8;
    const int f32mode = flags[0];

    if (blockIdx.x < BIN_BLOCKS) {
        // ---------------- bincount role ----------------
        const int i64 = flags[1];
        int* hist = (int*)smem;
        const bool use_lds = (nbkt <= MAX_BKT);
        if (use_lds) {
            for (int j = threadIdx.x; j < nbkt; j += 256) hist[j] = 0;
            __syncthreads();
        }
        const int stride = BIN_BLOCKS * 256;
        for (int e = blockIdx.x * 256 + threadIdx.x; e < n_edges; e += stride) {
            int d = i64 ? (int)((const long long*)dstp)[e] : ((const int*)dstp)[e];
            if ((unsigned)d >= (unsigned)n_nodes) continue;
            if (use_lds) atomicAdd(&hist[d >> NODE_SHIFT], 1);
            else         atomicAdd(&bucket_counts[d >> NODE_SHIFT], 1);
        }
        if (use_lds) {
            __syncthreads();
            for (int j = threadIdx.x; j < nbkt; j += 256) {
                int c = hist[j];
                if (c) atomicAdd(&bucket_counts[j], c);
            }
        }
        return;
    }

    // ---------------- gemm role ----------------
    char* wlds = smem;
    // stage W into LDS, swizzled: phys = logical ^ ((row&7)<<4)
    for (int c = threadIdx.x; c < 4096; c += 256) {
        const int L = c << 4;                 // logical byte (bf16 layout)
        const int row = L >> 9;               // 512 B per row
        const int phys = L ^ ((row & 7) << 4);
        short8 v;
        if (!f32mode) {
            v = *(const short8*)((const char*)wp + L);
        } else {
            const float* f = (const float*)wp + (L >> 1);
            floatx4 v0 = *(const floatx4*)f;
            floatx4 v1 = *(const floatx4*)(f + 4);
#pragma unroll
            for (int j = 0; j < 4; ++j) {
                v[j]     = f32_to_bf16_bits(v0[j]);
                v[4 + j] = f32_to_bf16_bits(v1[j]);
            }
        }
        *(short8*)(wlds + phys) = v;
    }
    __syncthreads();

    const int wid  = threadIdx.x >> 6;
    const int lane = threadIdx.x & 63;
    const int mrow = lane & 15;
    const int kg   = lane >> 4;
    const int swz  = (mrow & 7) << 4;

    auto loadA = [&](int tile, short8 (&a)[8]) {
        const int lrow = min(tile * 64 + wid * 16 + mrow, n_nodes - 1);
        if (!f32mode) {
            const short* fr = (const short*)featp + (size_t)lrow * F_IN;
#pragma unroll
            for (int ks = 0; ks < 8; ++ks)
                a[ks] = *(const short8*)(fr + ks * 32 + kg * 8);
        } else {
            const float* fr = (const float*)featp + (size_t)lrow * F_IN;
#pragma unroll
            for (int ks = 0; ks < 8; ++ks) {
                floatx4 v0 = *(const floatx4*)(fr + ks * 32 + kg * 8);
                floatx4 v1 = *(const floatx4*)(fr + ks * 32 + kg * 8 + 4);
                short8 t;
#pragma unroll
                for (int j = 0; j < 4; ++j) {
                    t[j]     = f32_to_bf16_bits(v0[j]);
                    t[4 + j] = f32_to_bf16_bits(v1[j]);
                }
                a[ks] = t;
            }
        }
    };

    auto compute = [&](int tile, short8 (&a)[8]) {
        floatx4 acc[8];
#pragma unroll
        for (int nt = 0; nt < 8; ++nt) acc[nt] = (floatx4){0.f, 0.f, 0.f, 0.f};
#pragma unroll
        for (int nt = 0; nt < 8; ++nt) {
            const int row = nt * 16 + mrow;
#pragma unroll
            for (int ks = 0; ks < 8; ++ks) {
                const int byte = (row << 9) + (ks << 6) + (kg << 4);
                const short8 b = *(const short8*)(wlds + (byte ^ swz));
                acc[nt] = __builtin_amdgcn_mfma_f32_16x16x32_bf16(a[ks], b, acc[nt], 0, 0, 0);
            }
        }
        const int m0 = tile * 64 + wid * 16;
#pragma unroll
        for (int nt = 0; nt < 8; ++nt) {
            const int col = nt * 16 + mrow;
#pragma unroll
            for (int r = 0; r < 4; ++r) {
                const int orow = m0 + kg * 4 + r;
                if (orow < n_nodes)
                    hp[(size_t)orow * F_OUT + col] = (unsigned short)f32_to_bf16_bits(acc[nt][r]);
            }
        }
    };

    int tile = blockIdx.x - BIN_BLOCKS;
    if (tile >= n_tiles) return;
    short8 a0[8], a1[8];
    loadA(tile, a0);
    bool cur0 = true;
    for (; tile < n_tiles; tile += GEMM_BLOCKS) {
        const int nxt = tile + GEMM_BLOCKS;
        if (cur0) {
            if (nxt < n_tiles) loadA(nxt, a1);
            compute(tile, a0);
        } else {
            if (nxt < n_tiles) loadA(nxt, a0);
            compute(tile, a1);
        }
        cur0 = !cur0;
    }
}

// Single-block exclusive scan over bucket_counts[nbkt] (nbkt <= 4096).
__global__ __launch_bounds__(256) void bucket_scan_kernel(
    const int* __restrict__ counts, int* __restrict__ offsets,
    int* __restrict__ cursor, int nbkt)
{
    __shared__ int lds[256];
    const int t = threadIdx.x;
    const int base = t * 16;
    int v[16];
    int run = 0;
#pragma unroll
    for (int j = 0; j < 16; ++j) {
        int idx = base + j;
        int x = (idx < nbkt) ? counts[idx] : 0;
        v[j] = run;
        run += x;
    }
    lds[t] = run;
    __syncthreads();
    for (int off = 1; off < 256; off <<= 1) {
        int x = (t >= off) ? lds[t - off] : 0;
        __syncthreads();
        lds[t] += x;
        __syncthreads();
    }
    const int excl = lds[t] - run;
#pragma unroll
    for (int j = 0; j < 16; ++j) {
        int idx = base + j;
        if (idx < nbkt) {
            int o = excl + v[j];
            offsets[idx] = o;
            cursor[idx]  = o;
        }
    }
}

// Chunked binfill: per-block LDS histogram -> one cursor atomic per
// (block,bucket) -> contiguous grouped writes of packed (src | ld<<24).
__global__ __launch_bounds__(256) void binfill_kernel(
    const void* __restrict__ srcp, const void* __restrict__ dstp,
    int* __restrict__ cursor, unsigned* __restrict__ bucket_edges,
    int n_edges, int n_nodes, int nbkt, const int* __restrict__ flags)
{
    const int i64 = flags[1];
    __shared__ int hist[MAX_BKT];
    __shared__ int base[MAX_BKT];

    if (nbkt > MAX_BKT) {  // fallback: direct atomics
        const int stride = gridDim.x * blockDim.x;
        for (int e = blockIdx.x * blockDim.x + threadIdx.x; e < n_edges; e += stride) {
            int s, d;
            if (i64) { s = (int)((const long long*)srcp)[e]; d = (int)((const long long*)dstp)[e]; }
            else     { s = ((const int*)srcp)[e];            d = ((const int*)dstp)[e]; }
            if ((unsigned)d >= (unsigned)n_nodes) continue;
            if ((unsigned)s >= (unsigned)n_nodes) s = 0;
            int pos = atomicAdd(&cursor[d >> NODE_SHIFT], 1);
            bucket_edges[pos] = (unsigned)s | ((unsigned)(d & (BKT_NODES - 1)) << 24);
        }
        return;
    }

    const int chunk = (n_edges + gridDim.x - 1) / gridDim.x;
    const int e0 = blockIdx.x * chunk;
    const int e1 = min(e0 + chunk, n_edges);

    for (int j = threadIdx.x; j < nbkt; j += 256) hist[j] = 0;
    __syncthreads();
    for (int e = e0 + threadIdx.x; e < e1; e += 256) {
        int d = i64 ? (int)((const long long*)dstp)[e] : ((const int*)dstp)[e];
        if ((unsigned)d < (unsigned)n_nodes) atomicAdd(&hist[d >> NODE_SHIFT], 1);
    }
    __syncthreads();
    for (int j = threadIdx.x; j < nbkt; j += 256) {
        int c = hist[j];
        base[j] = c ? atomicAdd(&cursor[j], c) : 0;
    }
    __syncthreads();
    for (int j = threadIdx.x; j < nbkt; j += 256) hist[j] = 0;
    __syncthreads();
    for (int e = e0 + threadIdx.x; e < e1; e += 256) {
        int s, d;
        if (i64) { s = (int)((const long long*)srcp)[e]; d = (int)((const long long*)dstp)[e]; }
        else     { s = ((const int*)srcp)[e];            d = ((const int*)dstp)[e]; }
        if ((unsigned)d >= (unsigned)n_nodes) continue;
        if ((unsigned)s >= (unsigned)n_nodes) s = 0;
        const int b = d >> NODE_SHIFT;
        int pos = base[b] + atomicAdd(&hist[b], 1);
        bucket_edges[pos] = (unsigned)s | ((unsigned)(d & (BKT_NODES - 1)) << 24);
    }
}

// One block per bucket: 64-bin local count + scan + scatter into the bucket's
// contiguous CSR region; emits exact per-node offsets/counts.
__global__ __launch_bounds__(256) void localsort_kernel(
    const unsigned* __restrict__ bucket_edges,
    const int* __restrict__ bucket_offsets, const int* __restrict__ bucket_counts,
    int* __restrict__ node_offsets, int* __restrict__ node_counts,
    int* __restrict__ sorted_src, int n_nodes)
{
    __shared__ int hist[BKT_NODES];
    __shared__ int excl[BKT_NODES];
    __shared__ int cur[BKT_NODES];
    const int bkt = blockIdx.x;
    const int beg = bucket_offsets[bkt];
    const int cnt = bucket_counts[bkt];
    const int tid = threadIdx.x;

    if (tid < BKT_NODES) hist[tid] = 0;
    __syncthreads();
    for (int i = tid; i < cnt; i += 256)
        atomicAdd(&hist[bucket_edges[beg + i] >> 24], 1);
    __syncthreads();
    if (tid == 0) {
        int run = 0;
        for (int j = 0; j < BKT_NODES; ++j) {
            excl[j] = run;
            cur[j] = run;
            run += hist[j];
        }
    }
    __syncthreads();
    if (tid < BKT_NODES) {
        const int node = (bkt << NODE_SHIFT) + tid;
        if (node < n_nodes) {
            node_counts[node]  = hist[tid];
            node_offsets[node] = beg + excl[tid];
        }
    }
    for (int i = tid; i < cnt; i += 256) {
        const unsigned pk = bucket_edges[beg + i];
        const int ld = pk >> 24;
        const int pos = beg + atomicAdd(&cur[ld], 1);
        sorted_src[pos] = (int)(pk & 0xFFFFFF);
    }
}

// Grid-strided waves: each wave owns ~n_nodes/(4*gridDim) nodes (degree
// averaging -> balance). Register accumulation, unroll 8, fused mean+bias.
__global__ __launch_bounds__(256) void agg_kernel(
    const unsigned short* __restrict__ h, const int* __restrict__ sorted_src,
    const int* __restrict__ node_offsets, const int* __restrict__ node_counts,
    const void* __restrict__ biasp, void* __restrict__ outp,
    int n_nodes, const int* __restrict__ flags)
{
    const int f32mode = flags[0];
    const int lane = threadIdx.x & 63;
    const int gwave = blockIdx.x * 4 + (threadIdx.x >> 6);
    const int nwaves = gridDim.x * 4;

    float bx, by;
    if (f32mode) {
        bx = ((const float*)biasp)[lane * 2];
        by = ((const float*)biasp)[lane * 2 + 1];
    } else {
        bx = bf16bits_to_f32(((const unsigned short*)biasp)[lane * 2]);
        by = bf16bits_to_f32(((const unsigned short*)biasp)[lane * 2 + 1]);
    }

    for (int node = gwave; node < n_nodes; node += nwaves) {
        const int beg = node_offsets[node];
        const int cnt = node_counts[node];

        float ax = 0.f, ay = 0.f;
        int i = 0;
        for (; i + 7 < cnt; i += 8) {
            int s[8];
#pragma unroll
            for (int j = 0; j < 8; ++j)
                s[j] = __builtin_nontemporal_load(&sorted_src[beg + i + j]);
#pragma unroll
            for (int j = 0; j < 8; ++j) {
                unsigned p = *(const unsigned*)(h + (size_t)s[j] * F_OUT + lane * 2);
                ax += bf16bits_to_f32((unsigned short)p);
                ay += bf16bits_to_f32((unsigned short)(p >> 16));
            }
        }
        for (; i < cnt; ++i) {
            int s = __builtin_nontemporal_load(&sorted_src[beg + i]);
            unsigned p = *(const unsigned*)(h + (size_t)s * F_OUT + lane * 2);
            ax += bf16bits_to_f32((unsigned short)p);
            ay += bf16bits_to_f32((unsigned short)(p >> 16));
        }

        const float scale = 1.0f / fmaxf((float)cnt, 1.0f);
        float ox = ax * scale + bx;
        float oy = ay * scale + by;

        if (f32mode) {
            __builtin_nontemporal_store(ox, (float*)outp + (size_t)node * F_OUT + lane * 2);
            __builtin_nontemporal_store(oy, (float*)outp + (size_t)node * F_OUT + lane * 2 + 1);
        } else {
            unsigned pk = ((unsigned)(unsigned short)f32_to_bf16_bits(oy) << 16) |
                          (unsigned)(unsigned short)f32_to_bf16_bits(ox);
            __builtin_nontemporal_store(pk, (unsigned*)outp + (size_t)node * (F_OUT / 2) + lane);
        }
    }
}

extern "C" void kernel_launch(void* const* d_in, const int* in_sizes, int n_in,
                              void* d_out, int out_size, void* d_ws, size_t ws_size,
                              hipStream_t stream)
{
    const void* feat = d_in[0];
    const void* w    = d_in[1];
    const void* bias = d_in[2];
    const void* src  = d_in[3];
    const void* dst  = d_in[4];
    const int n_nodes = in_sizes[0] / F_IN;
    const int n_edges = in_sizes[3];
    const int nbkt = (n_nodes + BKT_NODES - 1) / BKT_NODES;  // 1563 @ 100k

    char* ws = (char*)d_ws;
    auto align256 = [](size_t x) { return (x + 255) & ~(size_t)255; };

    size_t off = 0;
    int* flags = (int*)(ws + off);              off = align256(off + 256);
    int* bucket_counts = (int*)(ws + off);      off = align256(off + (size_t)nbkt * 4);
    int* bucket_offsets = (int*)(ws + off);     off = align256(off + (size_t)nbkt * 4);
    int* cursor = (int*)(ws + off);             off = align256(off + (size_t)nbkt * 4);
    unsigned* bucket_edges = (unsigned*)(ws + off);
    off = align256(off + (size_t)n_edges * 4);
    int* sorted_src = (int*)(ws + off);         off = align256(off + (size_t)n_edges * 4);
    int* node_offsets = (int*)(ws + off);       off = align256(off + (size_t)n_nodes * 4);
    int* node_counts = (int*)(ws + off);        off = align256(off + (size_t)n_nodes * 4);
    unsigned short* hp = (unsigned short*)(ws + off);
    off = align256(off + (size_t)n_nodes * F_OUT * 2);
    // total ~39.4 MB

    detect_kernel<<<1, 256, 0, stream>>>(feat, dst, flags, bucket_counts, nbkt);

    const int n_tiles = (n_nodes + 63) / 64;
    gemm_bincount_kernel<<<BIN_BLOCKS + GEMM_BLOCKS, 256, 0, stream>>>(
        feat, w, hp, n_nodes, n_tiles, dst, bucket_counts, n_edges, nbkt, flags);

    bucket_scan_kernel<<<1, 256, 0, stream>>>(bucket_counts, bucket_offsets,
                                              cursor, nbkt);
    binfill_kernel<<<512, 256, 0, stream>>>(src, dst, cursor, bucket_edges,
                                            n_edges, n_nodes, nbkt, flags);
    localsort_kernel<<<nbkt, 256, 0, stream>>>(bucket_edges, bucket_offsets,
                                               bucket_counts, node_offsets,
                                               node_counts, sorted_src, n_nodes);

    agg_kernel<<<2048, 256, 0, stream>>>(hp, sorted_src, node_offsets,
                                         node_counts, bias, d_out,
                                         n_nodes, flags);
}

// Round 7
// 170.273 us; speedup vs baseline: 1.1235x; 1.1235x over previous
//
#include <hip/hip_runtime.h>
#include <hip/hip_bf16.h>

typedef __attribute__((ext_vector_type(8))) short short8;
typedef __attribute__((ext_vector_type(4))) float floatx4;

#define F_IN 256
#define F_OUT 128
#define NODE_SHIFT 6               // 64 nodes per bucket
#define BKT_NODES 64
#define MAX_BKT 2048
#define FILL_BLOCKS 128            // hetero kernel: blocks [0,FILL_BLOCKS) do binfill
#define GEMM_BLOCKS 512            // blocks [FILL_BLOCKS, +GEMM_BLOCKS) do gemm
#define AGG_CAP 8192               // max edges per bucket handled by LDS sort path

static __device__ __forceinline__ short f32_to_bf16_bits(float v) {
    __hip_bfloat16 t = __float2bfloat16(v);
    return *reinterpret_cast<short*>(&t);
}
static __device__ __forceinline__ float bf16bits_to_f32(unsigned short u) {
    unsigned x = (unsigned)u << 16;
    return __builtin_bit_cast(float, x);
}

// Deterministic input-dtype probe + zero bucket_counts (folds the memset).
// flags[0]: 1 = floats are f32, 0 = floats are bf16
// flags[1]: 1 = indices are int64, 0 = int32
__global__ __launch_bounds__(256) void detect_kernel(
    const void* __restrict__ featp, const void* __restrict__ dstp,
    int* __restrict__ flags, int* __restrict__ bucket_counts, int nbkt)
{
    for (int j = threadIdx.x; j < nbkt; j += 256) bucket_counts[j] = 0;
    if (threadIdx.x == 0) {
        const unsigned short* fb = (const unsigned short*)featp;
        int plaus = 0;
        for (int i = 0; i < 64; ++i) {
            unsigned short u = fb[2 * i];
            int ex = (u >> 7) & 0xFF;
            if (ex >= 118 && ex <= 137) plaus++;
        }
        flags[0] = (plaus >= 48) ? 0 : 1;

        const int* di = (const int*)dstp;
        int zeros = 0;
        for (int i = 0; i < 64; ++i)
            if (di[2 * i + 1] == 0) zeros++;
        flags[1] = (zeros >= 62) ? 1 : 0;
    }
}

// LDS-histogram of dst>>NODE_SHIFT, global merge.
__global__ __launch_bounds__(256) void bincount_kernel(
    const void* __restrict__ dstp, int* __restrict__ bucket_counts,
    int n_edges, int n_nodes, int nbkt, const int* __restrict__ flags)
{
    const int i64 = flags[1];
    __shared__ int hist[MAX_BKT];
    const bool use_lds = (nbkt <= MAX_BKT);
    if (use_lds) {
        for (int j = threadIdx.x; j < nbkt; j += 256) hist[j] = 0;
        __syncthreads();
    }
    const int stride = gridDim.x * blockDim.x;
    for (int e = blockIdx.x * blockDim.x + threadIdx.x; e < n_edges; e += stride) {
        int d = i64 ? (int)((const long long*)dstp)[e] : ((const int*)dstp)[e];
        if ((unsigned)d >= (unsigned)n_nodes) continue;
        if (use_lds) atomicAdd(&hist[d >> NODE_SHIFT], 1);
        else         atomicAdd(&bucket_counts[d >> NODE_SHIFT], 1);
    }
    if (use_lds) {
        __syncthreads();
        for (int j = threadIdx.x; j < nbkt; j += 256) {
            int c = hist[j];
            if (c) atomicAdd(&bucket_counts[j], c);
        }
    }
}

// Single-block exclusive scan over bucket_counts[nbkt] (nbkt <= 4096).
__global__ __launch_bounds__(256) void bucket_scan_kernel(
    const int* __restrict__ counts, int* __restrict__ offsets,
    int* __restrict__ cursor, int nbkt)
{
    __shared__ int lds[256];
    const int t = threadIdx.x;
    const int base = t * 16;
    int v[16];
    int run = 0;
#pragma unroll
    for (int j = 0; j < 16; ++j) {
        int idx = base + j;
        int x = (idx < nbkt) ? counts[idx] : 0;
        v[j] = run;
        run += x;
    }
    lds[t] = run;
    __syncthreads();
    for (int off = 1; off < 256; off <<= 1) {
        int x = (t >= off) ? lds[t - off] : 0;
        __syncthreads();
        lds[t] += x;
        __syncthreads();
    }
    const int excl = lds[t] - run;
#pragma unroll
    for (int j = 0; j < 16; ++j) {
        int idx = base + j;
        if (idx < nbkt) {
            int o = excl + v[j];
            offsets[idx] = o;
            cursor[idx]  = o;
        }
    }
}

// Heterogeneous kernel:
//   blocks [0, FILL_BLOCKS):           chunked binfill (indep. of h)
//   blocks [FILL_BLOCKS, +GEMM_BLOCKS): h = feat @ w^T via MFMA, w in LDS
__global__ __launch_bounds__(256) void gemm_fill_kernel(
    const void* __restrict__ featp, const void* __restrict__ wp,
    unsigned short* __restrict__ hp, int n_nodes, int n_tiles,
    const void* __restrict__ srcp, const void* __restrict__ dstp,
    int* __restrict__ cursor, unsigned* __restrict__ bucket_edges,
    int n_edges, int nbkt, const int* __restrict__ flags)
{
    __shared__ short8 smem8[4096];   // 64 KB shared between both roles
    char* smem = (char*)smem8;
    const int f32mode = flags[0];

    if (blockIdx.x < FILL_BLOCKS) {
        // ---------------- binfill role ----------------
        const int i64 = flags[1];
        int* hist = (int*)smem;              // [MAX_BKT]
        int* base = (int*)smem + MAX_BKT;    // [MAX_BKT]

        if (nbkt > MAX_BKT) {  // fallback: direct atomics
            const int stride = FILL_BLOCKS * 256;
            for (int e = blockIdx.x * 256 + threadIdx.x; e < n_edges; e += stride) {
                int s, d;
                if (i64) { s = (int)((const long long*)srcp)[e]; d = (int)((const long long*)dstp)[e]; }
                else     { s = ((const int*)srcp)[e];            d = ((const int*)dstp)[e]; }
                if ((unsigned)d >= (unsigned)n_nodes) continue;
                if ((unsigned)s >= (unsigned)n_nodes) s = 0;
                int pos = atomicAdd(&cursor[d >> NODE_SHIFT], 1);
                bucket_edges[pos] = (unsigned)s | ((unsigned)(d & (BKT_NODES - 1)) << 24);
            }
            return;
        }

        const int chunk = (n_edges + FILL_BLOCKS - 1) / FILL_BLOCKS;
        const int e0 = blockIdx.x * chunk;
        const int e1 = min(e0 + chunk, n_edges);

        for (int j = threadIdx.x; j < nbkt; j += 256) hist[j] = 0;
        __syncthreads();
        for (int e = e0 + threadIdx.x; e < e1; e += 256) {
            int d = i64 ? (int)((const long long*)dstp)[e] : ((const int*)dstp)[e];
            if ((unsigned)d < (unsigned)n_nodes) atomicAdd(&hist[d >> NODE_SHIFT], 1);
        }
        __syncthreads();
        for (int j = threadIdx.x; j < nbkt; j += 256) {
            int c = hist[j];
            base[j] = c ? atomicAdd(&cursor[j], c) : 0;
        }
        __syncthreads();
        for (int j = threadIdx.x; j < nbkt; j += 256) hist[j] = 0;
        __syncthreads();
        for (int e = e0 + threadIdx.x; e < e1; e += 256) {
            int s, d;
            if (i64) { s = (int)((const long long*)srcp)[e]; d = (int)((const long long*)dstp)[e]; }
            else     { s = ((const int*)srcp)[e];            d = ((const int*)dstp)[e]; }
            if ((unsigned)d >= (unsigned)n_nodes) continue;
            if ((unsigned)s >= (unsigned)n_nodes) s = 0;
            const int b = d >> NODE_SHIFT;
            int pos = base[b] + atomicAdd(&hist[b], 1);
            bucket_edges[pos] = (unsigned)s | ((unsigned)(d & (BKT_NODES - 1)) << 24);
        }
        return;
    }

    // ---------------- gemm role ----------------
    char* wlds = smem;
    // stage W into LDS, swizzled: phys = logical ^ ((row&7)<<4)
    for (int c = threadIdx.x; c < 4096; c += 256) {
        const int L = c << 4;                 // logical byte (bf16 layout)
        const int row = L >> 9;               // 512 B per row
        const int phys = L ^ ((row & 7) << 4);
        short8 v;
        if (!f32mode) {
            v = *(const short8*)((const char*)wp + L);
        } else {
            const float* f = (const float*)wp + (L >> 1);
            floatx4 v0 = *(const floatx4*)f;
            floatx4 v1 = *(const floatx4*)(f + 4);
#pragma unroll
            for (int j = 0; j < 4; ++j) {
                v[j]     = f32_to_bf16_bits(v0[j]);
                v[4 + j] = f32_to_bf16_bits(v1[j]);
            }
        }
        *(short8*)(wlds + phys) = v;
    }
    __syncthreads();

    const int wid  = threadIdx.x >> 6;
    const int lane = threadIdx.x & 63;
    const int mrow = lane & 15;
    const int kg   = lane >> 4;
    const int swz  = (mrow & 7) << 4;

    auto loadA = [&](int tile, short8 (&a)[8]) {
        const int lrow = min(tile * 64 + wid * 16 + mrow, n_nodes - 1);
        if (!f32mode) {
            const short* fr = (const short*)featp + (size_t)lrow * F_IN;
#pragma unroll
            for (int ks = 0; ks < 8; ++ks)
                a[ks] = *(const short8*)(fr + ks * 32 + kg * 8);
        } else {
            const float* fr = (const float*)featp + (size_t)lrow * F_IN;
#pragma unroll
            for (int ks = 0; ks < 8; ++ks) {
                floatx4 v0 = *(const floatx4*)(fr + ks * 32 + kg * 8);
                floatx4 v1 = *(const floatx4*)(fr + ks * 32 + kg * 8 + 4);
                short8 t;
#pragma unroll
                for (int j = 0; j < 4; ++j) {
                    t[j]     = f32_to_bf16_bits(v0[j]);
                    t[4 + j] = f32_to_bf16_bits(v1[j]);
                }
                a[ks] = t;
            }
        }
    };

    auto compute = [&](int tile, short8 (&a)[8]) {
        floatx4 acc[8];
#pragma unroll
        for (int nt = 0; nt < 8; ++nt) acc[nt] = (floatx4){0.f, 0.f, 0.f, 0.f};
#pragma unroll
        for (int nt = 0; nt < 8; ++nt) {
            const int row = nt * 16 + mrow;
#pragma unroll
            for (int ks = 0; ks < 8; ++ks) {
                const int byte = (row << 9) + (ks << 6) + (kg << 4);
                const short8 b = *(const short8*)(wlds + (byte ^ swz));
                acc[nt] = __builtin_amdgcn_mfma_f32_16x16x32_bf16(a[ks], b, acc[nt], 0, 0, 0);
            }
        }
        const int m0 = tile * 64 + wid * 16;
#pragma unroll
        for (int nt = 0; nt < 8; ++nt) {
            const int col = nt * 16 + mrow;
#pragma unroll
            for (int r = 0; r < 4; ++r) {
                const int orow = m0 + kg * 4 + r;
                if (orow < n_nodes)
                    hp[(size_t)orow * F_OUT + col] = (unsigned short)f32_to_bf16_bits(acc[nt][r]);
            }
        }
    };

    int tile = blockIdx.x - FILL_BLOCKS;
    if (tile >= n_tiles) return;
    short8 a0[8], a1[8];
    loadA(tile, a0);
    bool cur0 = true;
    for (; tile < n_tiles; tile += GEMM_BLOCKS) {
        const int nxt = tile + GEMM_BLOCKS;
        if (cur0) {
            if (nxt < n_tiles) loadA(nxt, a1);
            compute(tile, a0);
        } else {
            if (nxt < n_tiles) loadA(nxt, a0);
            compute(tile, a1);
        }
        cur0 = !cur0;
    }
}

// One 1024-thread block per bucket: sort the bucket's packed edges in LDS
// (64-bin hist -> scan -> scatter), then 16 waves consume nodes via an LDS
// cursor (in-block load balance). Register accumulation, fused mean+bias.
__global__ __launch_bounds__(1024) void agg_kernel(
    const unsigned short* __restrict__ h, const unsigned* __restrict__ bucket_edges,
    const int* __restrict__ bucket_offsets, const int* __restrict__ bucket_counts,
    const void* __restrict__ biasp, void* __restrict__ outp,
    int n_nodes, const int* __restrict__ flags)
{
    __shared__ int s_src[AGG_CAP];        // 32 KB: src sorted by local dst
    __shared__ int hist[BKT_NODES];
    __shared__ int excl[BKT_NODES];
    __shared__ int cur64[BKT_NODES];
    __shared__ int node_cursor;

    const int f32mode = flags[0];
    const int bkt = blockIdx.x;
    const int beg = bucket_offsets[bkt];
    const int cnt = bucket_counts[bkt];
    const int tid = threadIdx.x;
    const int wave = tid >> 6;
    const int lane = tid & 63;
    const int node0 = bkt << NODE_SHIFT;

    float bx, by;
    if (f32mode) {
        bx = ((const float*)biasp)[lane * 2];
        by = ((const float*)biasp)[lane * 2 + 1];
    } else {
        bx = bf16bits_to_f32(((const unsigned short*)biasp)[lane * 2]);
        by = bf16bits_to_f32(((const unsigned short*)biasp)[lane * 2 + 1]);
    }

    if (cnt > AGG_CAP) {
        // rare fallback: scan-filter per node, no LDS sort
        for (int nl = wave; nl < BKT_NODES; nl += 16) {
            const int node = node0 + nl;
            if (node >= n_nodes) continue;
            float ax = 0.f, ay = 0.f;
            int deg = 0;
            for (int i = 0; i < cnt; ++i) {
                const unsigned pk = bucket_edges[beg + i];
                if ((int)(pk >> 24) == nl) {
                    const int s = (int)(pk & 0xFFFFFF);
                    unsigned p = *(const unsigned*)(h + (size_t)s * F_OUT + lane * 2);
                    ax += bf16bits_to_f32((unsigned short)p);
                    ay += bf16bits_to_f32((unsigned short)(p >> 16));
                    deg++;
                }
            }
            const float scale = 1.0f / fmaxf((float)deg, 1.0f);
            float ox = ax * scale + bx, oy = ay * scale + by;
            if (f32mode) {
                ((float*)outp)[(size_t)node * F_OUT + lane * 2]     = ox;
                ((float*)outp)[(size_t)node * F_OUT + lane * 2 + 1] = oy;
            } else {
                unsigned pkv = ((unsigned)(unsigned short)f32_to_bf16_bits(oy) << 16) |
                               (unsigned)(unsigned short)f32_to_bf16_bits(ox);
                ((unsigned*)outp)[(size_t)node * (F_OUT / 2) + lane] = pkv;
            }
        }
        return;
    }

    // ---- LDS counting sort by local dst ----
    if (tid < BKT_NODES) hist[tid] = 0;
    if (tid == 0) node_cursor = 0;
    __syncthreads();
    for (int i = tid; i < cnt; i += 1024)
        atomicAdd(&hist[bucket_edges[beg + i] >> 24], 1);
    __syncthreads();
    if (tid == 0) {
        int run = 0;
#pragma unroll
        for (int j = 0; j < BKT_NODES; ++j) {
            excl[j] = run;
            cur64[j] = run;
            run += hist[j];
        }
    }
    __syncthreads();
    for (int i = tid; i < cnt; i += 1024) {
        const unsigned pk = bucket_edges[beg + i];
        const int pos = atomicAdd(&cur64[pk >> 24], 1);
        s_src[pos] = (int)(pk & 0xFFFFFF);
    }
    __syncthreads();

    // ---- per-node accumulation, waves steal nodes from the LDS cursor ----
    for (;;) {
        int nl;
        if (lane == 0) nl = atomicAdd(&node_cursor, 1);
        nl = __shfl(nl, 0);
        if (nl >= BKT_NODES) break;
        const int node = node0 + nl;
        if (node >= n_nodes) continue;

        const int nbeg = excl[nl];
        const int ncnt = hist[nl];

        float ax = 0.f, ay = 0.f;
        int i = 0;
        for (; i + 7 < ncnt; i += 8) {
#pragma unroll
            for (int j = 0; j < 8; ++j) {
                const int s = s_src[nbeg + i + j];
                unsigned p = *(const unsigned*)(h + (size_t)s * F_OUT + lane * 2);
                ax += bf16bits_to_f32((unsigned short)p);
                ay += bf16bits_to_f32((unsigned short)(p >> 16));
            }
        }
        for (; i < ncnt; ++i) {
            const int s = s_src[nbeg + i];
            unsigned p = *(const unsigned*)(h + (size_t)s * F_OUT + lane * 2);
            ax += bf16bits_to_f32((unsigned short)p);
            ay += bf16bits_to_f32((unsigned short)(p >> 16));
        }

        const float scale = 1.0f / fmaxf((float)ncnt, 1.0f);
        float ox = ax * scale + bx, oy = ay * scale + by;
        if (f32mode) {
            ((float*)outp)[(size_t)node * F_OUT + lane * 2]     = ox;
            ((float*)outp)[(size_t)node * F_OUT + lane * 2 + 1] = oy;
        } else {
            unsigned pkv = ((unsigned)(unsigned short)f32_to_bf16_bits(oy) << 16) |
                           (unsigned)(unsigned short)f32_to_bf16_bits(ox);
            ((unsigned*)outp)[(size_t)node * (F_OUT / 2) + lane] = pkv;
        }
    }
}

extern "C" void kernel_launch(void* const* d_in, const int* in_sizes, int n_in,
                              void* d_out, int out_size, void* d_ws, size_t ws_size,
                              hipStream_t stream)
{
    const void* feat = d_in[0];
    const void* w    = d_in[1];
    const void* bias = d_in[2];
    const void* src  = d_in[3];
    const void* dst  = d_in[4];
    const int n_nodes = in_sizes[0] / F_IN;
    const int n_edges = in_sizes[3];
    const int nbkt = (n_nodes + BKT_NODES - 1) / BKT_NODES;  // 1563 @ 100k

    char* ws = (char*)d_ws;
    auto align256 = [](size_t x) { return (x + 255) & ~(size_t)255; };

    size_t off = 0;
    int* flags = (int*)(ws + off);              off = align256(off + 256);
    int* bucket_counts = (int*)(ws + off);      off = align256(off + (size_t)nbkt * 4);
    int* bucket_offsets = (int*)(ws + off);     off = align256(off + (size_t)nbkt * 4);
    int* cursor = (int*)(ws + off);             off = align256(off + (size_t)nbkt * 4);
    unsigned* bucket_edges = (unsigned*)(ws + off);
    off = align256(off + (size_t)n_edges * 4);
    unsigned short* hp = (unsigned short*)(ws + off);
    off = align256(off + (size_t)n_nodes * F_OUT * 2);
    // total ~32 MB

    detect_kernel<<<1, 256, 0, stream>>>(feat, dst, flags, bucket_counts, nbkt);

    bincount_kernel<<<256, 256, 0, stream>>>(dst, bucket_counts, n_edges,
                                             n_nodes, nbkt, flags);
    bucket_scan_kernel<<<1, 256, 0, stream>>>(bucket_counts, bucket_offsets,
                                              cursor, nbkt);

    const int n_tiles = (n_nodes + 63) / 64;
    gemm_fill_kernel<<<FILL_BLOCKS + GEMM_BLOCKS, 256, 0, stream>>>(
        feat, w, hp, n_nodes, n_tiles, src, dst, cursor, bucket_edges,
        n_edges, nbkt, flags);

    agg_kernel<<<nbkt, 1024, 0, stream>>>(hp, bucket_edges, bucket_offsets,
                                          bucket_counts, bias, d_out,
                                          n_nodes, flags);
}